// Round 4
// baseline (1157.294 us; speedup 1.0000x reference)
//
#include <hip/hip_runtime.h>

#define NB 1024
#define DS1 25
#define DS2 10
#define DF 128

// ================= Kernel A: gather + S2-mean (latency-optimized) =============
// grid = B*S1 = 25600 blocks x 128 threads, no LDS, low VGPR -> 32 waves/CU.
// Each block handles one (b,s1):
//   wsH[g][c] = features[samples1[g]][c]                (h1 row)
//   wsM[g][c] = mean_j features[samples2[g][j]][c]      (S2-mean row)
// All 11 independent 512B row-gathers are issued back-to-back; indices are
// blockIdx-uniform -> scalar loads.
__global__ __launch_bounds__(128, 8)
void sage_gather_kernel(const float* __restrict__ features,
                        const int* __restrict__ samples1,
                        const int* __restrict__ samples2,
                        float* __restrict__ wsH,
                        float* __restrict__ wsM)
{
    const int g = blockIdx.x;       // b*DS1 + s1
    const int c = threadIdx.x;      // feature column 0..127

    const int i1 = samples1[g];
    const int* __restrict__ i2 = samples2 + (size_t)g * DS2;

    int idx[DS2];
    #pragma unroll
    for (int j = 0; j < DS2; ++j) idx[j] = i2[j];

    // issue the h1 gather first, then the 10 h2 gathers -> 11 loads in flight
    const float hv = features[(size_t)i1 * DF + c];

    float p = 0.f;
    #pragma unroll
    for (int j = 0; j < DS2; ++j)
        p += features[(size_t)idx[j] * DF + c];

    wsH[(size_t)g * DF + c] = hv;
    wsM[(size_t)g * DF + c] = p * 0.1f;
}

// ================= Kernel B: compute (verified matmul structure) ==============
// One block per b. Same layer-1/layer-2 math as the verified fused kernel,
// but Xs/M2 rows stream in coalesced from the workspace instead of gathering.
__global__ __launch_bounds__(256, 4)
void sage_compute_kernel(const float* __restrict__ features,
                         const float* __restrict__ w_self0,
                         const float* __restrict__ w_neigh0,
                         const float* __restrict__ w_self1,
                         const float* __restrict__ w_neigh1,
                         const int* __restrict__ samples0,
                         const float* __restrict__ wsH,
                         const float* __restrict__ wsM,
                         float* __restrict__ out)
{
    __shared__ float Xs[28][DF];     // rows 0..24 = h1, row 25 = h0, 26/27 pad
    __shared__ float M2[28][DF];     // rows 0..24 = mean_s2(h2), row 25 = mean_s1(h1)
    __shared__ float Npart[4][256];
    __shared__ float n0s[256];
    __shared__ float N1s[256];

    const int b = blockIdx.x;
    const int t = threadIdx.x;
    const int c = t & 127;
    const int h = t >> 7;

    // ---- coalesced streaming of staged rows (25*128 = 3200 floats each) ----
    const float* __restrict__ srcH = wsH + (size_t)b * DS1 * DF;
    const float* __restrict__ srcM = wsM + (size_t)b * DS1 * DF;
    float* dstX = &Xs[0][0];
    float* dstM = &M2[0][0];
    for (int i = t * 4; i < DS1 * DF; i += 1024) {
        *(float4*)(dstX + i) = *(const float4*)(srcH + i);
        *(float4*)(dstM + i) = *(const float4*)(srcM + i);
    }
    if (h == 0) {
        const int s0 = samples0[b];
        Xs[25][c] = features[(size_t)s0 * DF + c];
        Xs[26][c] = 0.f; Xs[27][c] = 0.f;
        M2[26][c] = 0.f; M2[27][c] = 0.f;
    }
    __syncthreads();

    // mean over s1 of h1 -> M2[25]
    if (h == 0) {
        float s = 0.f;
        #pragma unroll
        for (int r = 0; r < DS1; ++r) s += Xs[r][c];
        M2[25][c] = s * (1.0f / 25.0f);
    }
    __syncthreads();

    // ---- layer-1 batched matmul: 26 rows x 256 cols, K=128 ----
    const int w = t >> 6;                 // wave id: rows w, w+4, ..., (R=7)
    const int l = t & 63;                 // lane
    const int half = l >> 5;              // 0: self-path (Xs,Ws0)  1: neigh (M2,Wn0)
    const int co = (l & 31) * 4;          // col within the 128-wide half
    const float* __restrict__ W1 = half ? w_neigh0 : w_self0;

    float acc[7][4];
    #pragma unroll
    for (int j = 0; j < 7; ++j) {
        #pragma unroll
        for (int cc = 0; cc < 4; ++cc) acc[j][cc] = 0.f;
    }

    for (int kb = 0; kb < 32; ++kb) {
        float4 xv[7];
        #pragma unroll
        for (int j = 0; j < 7; ++j) {
            const int r = w + 4 * j;                 // up to 27 (padded rows zero)
            const float* row = half ? &M2[r][0] : &Xs[r][0];
            xv[j] = *(const float4*)(row + kb * 4);  // broadcast ds_read_b128
        }
        #pragma unroll
        for (int kk = 0; kk < 4; ++kk) {
            const float4 wv = *(const float4*)(W1 + (kb * 4 + kk) * DF + co);
            #pragma unroll
            for (int j = 0; j < 7; ++j) {
                const float x = ((const float*)&xv[j])[kk];
                acc[j][0] = fmaf(x, wv.x, acc[j][0]);
                acc[j][1] = fmaf(x, wv.y, acc[j][1]);
                acc[j][2] = fmaf(x, wv.z, acc[j][2]);
                acc[j][3] = fmaf(x, wv.w, acc[j][3]);
            }
        }
    }

    // relu; rows <25 -> N1 partial sum; row 25 -> n0
    const int ocol = half * 128 + co;
    float pn[4] = {0.f, 0.f, 0.f, 0.f};
    #pragma unroll
    for (int j = 0; j < 7; ++j) {
        const int r = w + 4 * j;
        #pragma unroll
        for (int cc = 0; cc < 4; ++cc) {
            const float v = fmaxf(acc[j][cc], 0.f);
            if (r < 25) pn[cc] += v;
            else if (r == 25) n0s[ocol + cc] = v;   // only wave 1, j==6
        }
    }
    #pragma unroll
    for (int cc = 0; cc < 4; ++cc) Npart[w][ocol + cc] = pn[cc];
    __syncthreads();

    N1s[t] = (Npart[0][t] + Npart[1][t] + Npart[2][t] + Npart[3][t]) * (1.0f / 25.0f);
    __syncthreads();

    // ---- layer-2: out = relu(concat(n0 @ Ws1, N1mean @ Wn1)), K=256 over waves
    const float* __restrict__ W2 = half ? w_neigh1 : w_self1;
    const float* __restrict__ X2 = half ? N1s : n0s;
    float a2[4] = {0.f, 0.f, 0.f, 0.f};
    #pragma unroll
    for (int kb = 0; kb < 16; ++kb) {
        const int k0 = w * 64 + kb * 4;
        const float4 x4 = *(const float4*)(X2 + k0);
        #pragma unroll
        for (int kk = 0; kk < 4; ++kk) {
            const float4 wv = *(const float4*)(W2 + (k0 + kk) * 128 + co);
            const float x = ((const float*)&x4)[kk];
            a2[0] = fmaf(x, wv.x, a2[0]);
            a2[1] = fmaf(x, wv.y, a2[1]);
            a2[2] = fmaf(x, wv.z, a2[2]);
            a2[3] = fmaf(x, wv.w, a2[3]);
        }
    }
    #pragma unroll
    for (int cc = 0; cc < 4; ++cc) Npart[w][ocol + cc] = a2[cc];
    __syncthreads();

    const float v = Npart[0][t] + Npart[1][t] + Npart[2][t] + Npart[3][t];
    out[(size_t)b * 256 + t] = fmaxf(v, 0.f);
}

// ================= Fallback: original verified fused kernel ===================
__global__ __launch_bounds__(256, 4)
void sage_fused_kernel(const float* __restrict__ features,
                       const float* __restrict__ w_self0,
                       const float* __restrict__ w_neigh0,
                       const float* __restrict__ w_self1,
                       const float* __restrict__ w_neigh1,
                       const int* __restrict__ samples0,
                       const int* __restrict__ samples1,
                       const int* __restrict__ samples2,
                       float* __restrict__ out)
{
    __shared__ float Xs[28][DF];
    __shared__ float M2[28][DF];
    __shared__ float Npart[4][256];
    __shared__ float n0s[256];
    __shared__ float N1s[256];

    const int b = blockIdx.x;
    const int t = threadIdx.x;
    const int c = t & 127;
    const int h = t >> 7;

    if (h == 0) {
        const int s0 = samples0[b];
        Xs[25][c] = features[(size_t)s0 * DF + c];
        Xs[26][c] = 0.f; Xs[27][c] = 0.f;
        M2[26][c] = 0.f; M2[27][c] = 0.f;
    }
    for (int s1 = h; s1 < DS1; s1 += 2) {
        const int i1 = samples1[b * DS1 + s1];
        const int* i2 = samples2 + (size_t)(b * DS1 + s1) * DS2;
        float p = 0.f;
        #pragma unroll
        for (int j = 0; j < DS2; ++j)
            p += features[(size_t)i2[j] * DF + c];
        M2[s1][c] = p * 0.1f;
        Xs[s1][c] = features[(size_t)i1 * DF + c];
    }
    __syncthreads();

    if (h == 0) {
        float s = 0.f;
        #pragma unroll
        for (int r = 0; r < DS1; ++r) s += Xs[r][c];
        M2[25][c] = s * (1.0f / 25.0f);
    }
    __syncthreads();

    const int w = t >> 6;
    const int l = t & 63;
    const int half = l >> 5;
    const int co = (l & 31) * 4;
    const float* __restrict__ W1 = half ? w_neigh0 : w_self0;

    float acc[7][4];
    #pragma unroll
    for (int j = 0; j < 7; ++j) {
        #pragma unroll
        for (int cc = 0; cc < 4; ++cc) acc[j][cc] = 0.f;
    }

    for (int kb = 0; kb < 32; ++kb) {
        float4 xv[7];
        #pragma unroll
        for (int j = 0; j < 7; ++j) {
            const int r = w + 4 * j;
            const float* row = half ? &M2[r][0] : &Xs[r][0];
            xv[j] = *(const float4*)(row + kb * 4);
        }
        #pragma unroll
        for (int kk = 0; kk < 4; ++kk) {
            const float4 wv = *(const float4*)(W1 + (kb * 4 + kk) * DF + co);
            #pragma unroll
            for (int j = 0; j < 7; ++j) {
                const float x = ((const float*)&xv[j])[kk];
                acc[j][0] = fmaf(x, wv.x, acc[j][0]);
                acc[j][1] = fmaf(x, wv.y, acc[j][1]);
                acc[j][2] = fmaf(x, wv.z, acc[j][2]);
                acc[j][3] = fmaf(x, wv.w, acc[j][3]);
            }
        }
    }

    const int ocol = half * 128 + co;
    float pn[4] = {0.f, 0.f, 0.f, 0.f};
    #pragma unroll
    for (int j = 0; j < 7; ++j) {
        const int r = w + 4 * j;
        #pragma unroll
        for (int cc = 0; cc < 4; ++cc) {
            const float v = fmaxf(acc[j][cc], 0.f);
            if (r < 25) pn[cc] += v;
            else if (r == 25) n0s[ocol + cc] = v;
        }
    }
    #pragma unroll
    for (int cc = 0; cc < 4; ++cc) Npart[w][ocol + cc] = pn[cc];
    __syncthreads();

    N1s[t] = (Npart[0][t] + Npart[1][t] + Npart[2][t] + Npart[3][t]) * (1.0f / 25.0f);
    __syncthreads();

    const float* __restrict__ W2 = half ? w_neigh1 : w_self1;
    const float* __restrict__ X2 = half ? N1s : n0s;
    float a2[4] = {0.f, 0.f, 0.f, 0.f};
    #pragma unroll
    for (int kb = 0; kb < 16; ++kb) {
        const int k0 = w * 64 + kb * 4;
        const float4 x4 = *(const float4*)(X2 + k0);
        #pragma unroll
        for (int kk = 0; kk < 4; ++kk) {
            const float4 wv = *(const float4*)(W2 + (k0 + kk) * 128 + co);
            const float x = ((const float*)&x4)[kk];
            a2[0] = fmaf(x, wv.x, a2[0]);
            a2[1] = fmaf(x, wv.y, a2[1]);
            a2[2] = fmaf(x, wv.z, a2[2]);
            a2[3] = fmaf(x, wv.w, a2[3]);
        }
    }
    #pragma unroll
    for (int cc = 0; cc < 4; ++cc) Npart[w][ocol + cc] = a2[cc];
    __syncthreads();

    const float v = Npart[0][t] + Npart[1][t] + Npart[2][t] + Npart[3][t];
    out[(size_t)b * 256 + t] = fmaxf(v, 0.f);
}

extern "C" void kernel_launch(void* const* d_in, const int* in_sizes, int n_in,
                              void* d_out, int out_size, void* d_ws, size_t ws_size,
                              hipStream_t stream) {
    const float* features = (const float*)d_in[0];
    const float* w_self0  = (const float*)d_in[1];
    const float* w_neigh0 = (const float*)d_in[2];
    const float* w_self1  = (const float*)d_in[3];
    const float* w_neigh1 = (const float*)d_in[4];
    const int* samples0 = (const int*)d_in[5];
    const int* samples1 = (const int*)d_in[6];
    const int* samples2 = (const int*)d_in[7];
    float* out = (float*)d_out;

    const size_t rows = (size_t)NB * DS1 * DF;          // 3,276,800 floats
    const size_t need = 2 * rows * sizeof(float);       // 26.2 MB

    if (ws_size >= need) {
        float* wsH = (float*)d_ws;
        float* wsM = wsH + rows;
        sage_gather_kernel<<<dim3(NB * DS1), dim3(128), 0, stream>>>(
            features, samples1, samples2, wsH, wsM);
        sage_compute_kernel<<<dim3(NB), dim3(256), 0, stream>>>(
            features, w_self0, w_neigh0, w_self1, w_neigh1,
            samples0, wsH, wsM, out);
    } else {
        sage_fused_kernel<<<dim3(NB), dim3(256), 0, stream>>>(
            features, w_self0, w_neigh0, w_self1, w_neigh1,
            samples0, samples1, samples2, out);
    }
}